// Round 12
// baseline (253.022 us; speedup 1.0000x reference)
//
#include <hip/hip_runtime.h>
#include <hip/hip_bf16.h>

#define B_ 4
#define T_ 2048
#define E_ 1024
#define H_ 16
#define DH_ 64
#define QSCALE_ 0.18033688f   // 0.125 * log2(e): QK^T comes out in log2 domain

typedef __attribute__((ext_vector_type(8))) short bf16x8;
typedef __attribute__((ext_vector_type(4))) float f32x4;
typedef unsigned int u32;

__device__ inline ushort f2bf(float f) {
    union { float f; unsigned u; } v; v.f = f;
    unsigned r = (v.u + 0x7fffu + ((v.u >> 16) & 1u)) >> 16;
    return (ushort)r;
}

// pack two f32 -> two bf16 (truncation) in one v_perm_b32: a->low, b->high
__device__ inline u32 pack2bf(float a, float b) {
    union { float f; u32 u; } ua, ub; ua.f = a; ub.f = b;
    return __builtin_amdgcn_perm(ub.u, ua.u, 0x07060302);
}

__device__ inline void gload16(const ushort* g, ushort* l) {
    __builtin_amdgcn_global_load_lds((const __attribute__((address_space(1))) u32*)g,
                                     (__attribute__((address_space(3))) u32*)l, 16, 0, 0);
}

// ---------------- fused f32 -> bf16 convert ----------------
__global__ void cvt_all(const float* __restrict__ x, const float* __restrict__ wq,
                        const float* __restrict__ wp,
                        ushort* __restrict__ xo, ushort* __restrict__ wqo, ushort* __restrict__ wpo)
{
    const int NX = B_ * T_ * E_ / 4;
    const int NW = 3 * E_ * E_ / 4;
    int i = blockIdx.x * 256 + threadIdx.x;
    const float* s; ushort* d; int off;
    if (i < NX)            { s = x;  d = xo;  off = i; }
    else if (i < NX + NW)  { s = wq; d = wqo; off = i - NX; }
    else                   { s = wp; d = wpo; off = i - NX - NW; }
    float4 f = ((const float4*)s)[off];
    ushort4 u;
    u.x = f2bf(f.x); u.y = f2bf(f.y); u.z = f2bf(f.z); u.w = f2bf(f.w);
    ((ushort4*)d)[off] = u;
}

// ---------------- QKV GEMM: 128x128 tile, BK=64, XOR-swizzled LDS (R11-proven) ----------------
__global__ __launch_bounds__(256) void gemm_qkv(
    const ushort* __restrict__ Xb, const ushort* __restrict__ Wb,
    const float* __restrict__ bias,
    ushort* __restrict__ Q, ushort* __restrict__ K, ushort* __restrict__ Vt)
{
    __shared__ ushort As[128 * 64];
    __shared__ ushort Bs[128 * 64];
    const int m0 = blockIdx.x * 128;
    const int n0 = blockIdx.y * 128;
    const int kind = n0 >> 10;           // 0=Q 1=K 2=V (block-uniform)
    const int tid  = threadIdx.x;
    const int wave = tid >> 6, lane = tid & 63;
    const int lrow = lane & 15, quad = lane >> 4;
    const int srow8 = lane >> 3;
    const int scol8 = ((lane & 7) ^ srow8) * 8;   // XOR-swizzled source column

    const ushort* gA = Xb + (size_t)(m0 + wave * 8 + srow8) * 1024 + scol8;
    const ushort* gB = Wb + (size_t)(n0 + wave * 8 + srow8) * 1024 + scol8;

    const int mw = (wave >> 1) * 64, nw = (wave & 1) * 64;
    const int rsw = (lrow & 7);

    f32x4 acc[4][4];
#pragma unroll
    for (int i = 0; i < 4; i++)
#pragma unroll
        for (int j = 0; j < 4; j++) acc[i][j] = f32x4{0.f, 0.f, 0.f, 0.f};

    const int b = m0 >> 11;
    const bool ct = (kind != 2);

    for (int k0 = 0; k0 < 1024; k0 += 64) {
        __syncthreads();
#pragma unroll
        for (int g = 0; g < 4; g++) {
            gload16(gA + (size_t)g * 32 * 1024 + k0, &As[(g * 32 + wave * 8) * 64]);
            gload16(gB + (size_t)g * 32 * 1024 + k0, &Bs[(g * 32 + wave * 8) * 64]);
        }
        __syncthreads();
#pragma unroll
        for (int ks = 0; ks < 2; ks++) {
            const int usw = ((ks * 4 + quad) ^ rsw) * 8;
            bf16x8 a[4], bfr[4];
#pragma unroll
            for (int i = 0; i < 4; i++)
                a[i] = *(const bf16x8*)&As[(mw + i * 16 + lrow) * 64 + usw];
#pragma unroll
            for (int j = 0; j < 4; j++)
                bfr[j] = *(const bf16x8*)&Bs[(nw + j * 16 + lrow) * 64 + usw];
            if (ct) {
#pragma unroll
                for (int i = 0; i < 4; i++)
#pragma unroll
                    for (int j = 0; j < 4; j++)
                        acc[i][j] = __builtin_amdgcn_mfma_f32_16x16x32_bf16(bfr[j], a[i], acc[i][j], 0, 0, 0);
            } else {
#pragma unroll
                for (int i = 0; i < 4; i++)
#pragma unroll
                    for (int j = 0; j < 4; j++)
                        acc[i][j] = __builtin_amdgcn_mfma_f32_16x16x32_bf16(a[i], bfr[j], acc[i][j], 0, 0, 0);
            }
        }
    }

    if (ct) {
        ushort* dst = (kind == 0) ? Q : K;
        const float scale = (kind == 0) ? QSCALE_ : 1.f;
#pragma unroll
        for (int j = 0; j < 4; j++) {
            int nq = (n0 & 1023) + nw + j * 16 + quad * 4;
            int h = nq >> 6, d = nq & 63;
            float4 bv = *(const float4*)&bias[n0 + nw + j * 16 + quad * 4];
            size_t bh = (size_t)(b * H_ + h);
#pragma unroll
            for (int i = 0; i < 4; i++) {
                int t = (m0 + mw + i * 16 + lrow) & 2047;   // batch-local!
                ushort4 o;
                o.x = f2bf((acc[i][j][0] + bv.x) * scale);
                o.y = f2bf((acc[i][j][1] + bv.y) * scale);
                o.z = f2bf((acc[i][j][2] + bv.z) * scale);
                o.w = f2bf((acc[i][j][3] + bv.w) * scale);
                *(ushort4*)&dst[(bh * T_ + t) * DH_ + d] = o;
            }
        }
    } else {
#pragma unroll
        for (int j = 0; j < 4; j++) {
            int nv = (n0 & 1023) + nw + j * 16 + lrow;
            int h = nv >> 6, d = nv & 63;
            float bv = bias[n0 + nw + j * 16 + lrow];
            size_t bh = (size_t)(b * H_ + h);
#pragma unroll
            for (int i = 0; i < 4; i++) {
                int t = (m0 + mw + i * 16 + quad * 4) & 2047;   // batch-local!
                ushort4 o;
                o.x = f2bf(acc[i][j][0] + bv);
                o.y = f2bf(acc[i][j][1] + bv);
                o.z = f2bf(acc[i][j][2] + bv);
                o.w = f2bf(acc[i][j][3] + bv);
                *(ushort4*)&Vt[(bh * DH_ + d) * T_ + t] = o;
            }
        }
    }
}

// ---------------- Flash attention: paired q-tiles, double-buffered K/V ----------------
// R8 body; K/V staged into alternating LDS buffers -> ONE barrier per 64-key
// tile instead of two. Next tile's regs are ds_written late in the body so the
// vmcnt drain lands after compute. P packed as b64 writes.
#define LDT_ 76

__global__ __launch_bounds__(256) void flash_attn(
    const ushort* __restrict__ Q, const ushort* __restrict__ K,
    const ushort* __restrict__ Vg,   // [bh][DH][T]
    ushort* __restrict__ O)
{
    __shared__ ushort Ks[2][64 * LDT_];
    __shared__ ushort Vt[2][64 * LDT_];
    __shared__ ushort Ps[128 * LDT_];   // doubles as Q staging

    const int qtA = 15 - blockIdx.x;     // long tile
    const int qtB = blockIdx.x;          // short tile
    const int bh = blockIdx.y;
    const int tid  = threadIdx.x;
    const int wave = tid >> 6, lane = tid & 63;
    const int lrow = lane & 15, quad = lane >> 4;
    const int sr = tid >> 2, sc = (tid & 3) * 16;   // K/V staging coords

    const ushort* Qbh = Q  + (size_t)bh * T_ * DH_;
    const ushort* Kbh = K  + (size_t)bh * T_ * DH_;
    const ushort* Vbh = Vg + (size_t)bh * DH_ * T_;
    const int b_ = bh >> 4, h_ = bh & 15;

    auto stageQ = [&](int qt, bf16x8 qa[2][2]) {
        int qr = tid >> 1, qc = (tid & 1) * 32;
        const ushort* src = &Qbh[(size_t)(qt * 128 + qr) * DH_ + qc];
#pragma unroll
        for (int i = 0; i < 4; i++)
            *(int4*)&Ps[qr * LDT_ + qc + 8 * i] = *(const int4*)&src[8 * i];
        __syncthreads();
#pragma unroll
        for (int s = 0; s < 2; s++)
#pragma unroll
            for (int h = 0; h < 2; h++)
                qa[s][h] = *(const bf16x8*)&Ps[(s * 64 + wave * 16 + lrow) * LDT_ + h * 32 + quad * 8];
    };

    bf16x8 qaA[2][2], qaB[2][2];
    stageQ(qtA, qaA);
    __syncthreads();
    stageQ(qtB, qaB);
    // run()'s prologue barrier protects the qa reads above before LDS reuse

    auto run = [&](const bf16x8 (&qa)[2][2], int qt) {
        const int lastkt = 2 * qt + 1;

        int4 kr0 = *(const int4*)&Kbh[(size_t)sr * DH_ + sc];
        int4 kr1 = *(const int4*)&Kbh[(size_t)sr * DH_ + sc + 8];
        int4 vr0 = *(const int4*)&Vbh[(size_t)sr * T_ + sc];
        int4 vr1 = *(const int4*)&Vbh[(size_t)sr * T_ + sc + 8];

        float ls[2] = {0.f, 0.f};
        f32x4 accO[2][4];
#pragma unroll
        for (int s = 0; s < 2; s++)
#pragma unroll
            for (int j = 0; j < 4; j++) accO[s][j] = f32x4{0.f, 0.f, 0.f, 0.f};

        __syncthreads();   // previous users of LDS done
        *(int4*)&Ks[0][sr * LDT_ + sc]     = kr0;
        *(int4*)&Ks[0][sr * LDT_ + sc + 8] = kr1;
        *(int4*)&Vt[0][sr * LDT_ + sc]     = vr0;
        *(int4*)&Vt[0][sr * LDT_ + sc + 8] = vr1;
        __syncthreads();   // buf 0 visible

        for (int kt = 0; kt <= lastkt; ++kt) {
            const int p = kt & 1;
            if (kt < lastkt) {   // issue next tile's loads; land during compute
                kr0 = *(const int4*)&Kbh[(size_t)((kt + 1) * 64 + sr) * DH_ + sc];
                kr1 = *(const int4*)&Kbh[(size_t)((kt + 1) * 64 + sr) * DH_ + sc + 8];
                vr0 = *(const int4*)&Vbh[(size_t)sr * T_ + (kt + 1) * 64 + sc];
                vr1 = *(const int4*)&Vbh[(size_t)sr * T_ + (kt + 1) * 64 + sc + 8];
            }

            bf16x8 kb0[4], kb1[4];
#pragma unroll
            for (int j = 0; j < 4; j++) {
                kb0[j] = *(const bf16x8*)&Ks[p][(j * 16 + lrow) * LDT_ + quad * 8];
                kb1[j] = *(const bf16x8*)&Ks[p][(j * 16 + lrow) * LDT_ + 32 + quad * 8];
            }

            const bool do0 = (kt != lastkt);
#pragma unroll
            for (int s = 0; s < 2; s++) {
                if (s == 0 && !do0) continue;
                f32x4 st[4];
#pragma unroll
                for (int j = 0; j < 4; j++) {
                    f32x4 sj = f32x4{0.f, 0.f, 0.f, 0.f};
                    sj = __builtin_amdgcn_mfma_f32_16x16x32_bf16(kb0[j], qa[s][0], sj, 0, 0, 0);
                    sj = __builtin_amdgcn_mfma_f32_16x16x32_bf16(kb1[j], qa[s][1], sj, 0, 0, 0);
                    st[j] = sj;
                }
                if (kt == 2 * qt + s) {
                    const int qrow = qt * 128 + s * 64 + wave * 16 + lrow;
                    const int keyb = kt * 64 + quad * 4;
#pragma unroll
                    for (int j = 0; j < 4; j++)
#pragma unroll
                        for (int r = 0; r < 4; r++)
                            if (keyb + j * 16 + r > qrow) st[j][r] = -1e30f;
                }
                float lp = 0.f;
#pragma unroll
                for (int j = 0; j < 4; j++)
#pragma unroll
                    for (int r = 0; r < 4; r++) {
                        float p2 = __builtin_amdgcn_exp2f(st[j][r]);
                        st[j][r] = p2;
                        lp += p2;
                    }
                ls[s] += lp;
                ushort* prow = &Ps[(s * 64 + wave * 16 + lrow) * LDT_ + quad * 4];
#pragma unroll
                for (int j = 0; j < 4; j++) {
                    uint2 pw;
                    pw.x = pack2bf(st[j][0], st[j][1]);
                    pw.y = pack2bf(st[j][2], st[j][3]);
                    *(uint2*)&prow[j * 16] = pw;
                }
            }

            bf16x8 vb0[4], vb1[4];
#pragma unroll
            for (int j = 0; j < 4; j++) {
                vb0[j] = *(const bf16x8*)&Vt[p][(j * 16 + lrow) * LDT_ + quad * 8];
                vb1[j] = *(const bf16x8*)&Vt[p][(j * 16 + lrow) * LDT_ + 32 + quad * 8];
            }
#pragma unroll
            for (int s = 0; s < 2; s++) {
                if (s == 0 && !do0) continue;
                bf16x8 pa0 = *(const bf16x8*)&Ps[(s * 64 + wave * 16 + lrow) * LDT_ + quad * 8];
                bf16x8 pa1 = *(const bf16x8*)&Ps[(s * 64 + wave * 16 + lrow) * LDT_ + 32 + quad * 8];
#pragma unroll
                for (int jd = 0; jd < 4; jd++) {
                    accO[s][jd] = __builtin_amdgcn_mfma_f32_16x16x32_bf16(pa0, vb0[jd], accO[s][jd], 0, 0, 0);
                    accO[s][jd] = __builtin_amdgcn_mfma_f32_16x16x32_bf16(pa1, vb1[jd], accO[s][jd], 0, 0, 0);
                }
            }

            if (kt < lastkt) {   // stage next tile into the other buffer
                *(int4*)&Ks[p ^ 1][sr * LDT_ + sc]     = kr0;
                *(int4*)&Ks[p ^ 1][sr * LDT_ + sc + 8] = kr1;
                *(int4*)&Vt[p ^ 1][sr * LDT_ + sc]     = vr0;
                *(int4*)&Vt[p ^ 1][sr * LDT_ + sc + 8] = vr1;
            }
            __syncthreads();     // one barrier per tile
        }

#pragma unroll
        for (int s = 0; s < 2; s++) {
            ls[s] += __shfl_xor(ls[s], 16, 64);
            ls[s] += __shfl_xor(ls[s], 32, 64);
        }
#pragma unroll
        for (int s = 0; s < 2; s++) {
#pragma unroll
            for (int r = 0; r < 4; r++) {
                float lv = __shfl(ls[s], quad * 4 + r, 64);
                float inv = 1.f / lv;
                int t = qt * 128 + s * 64 + wave * 16 + quad * 4 + r;
#pragma unroll
                for (int jd = 0; jd < 4; jd++) {
                    int d = jd * 16 + lrow;
                    O[((size_t)(b_ * T_ + t)) * E_ + h_ * DH_ + d] = f2bf(accO[s][jd][r] * inv);
                }
            }
        }
    };

    run(qaA, qtA);
    run(qaB, qtB);
}

// ---------------- proj GEMM: 128x64 tile (grid 1024 = 4/CU), BK=64, swizzled, C^T ----------------
__global__ __launch_bounds__(256) void gemm_proj(
    const ushort* __restrict__ Ob, const ushort* __restrict__ Wb,
    const float* __restrict__ bias, float* __restrict__ out)
{
    __shared__ ushort As[128 * 64];
    __shared__ ushort Bs[64 * 64];
    const int m0 = blockIdx.x * 128;
    const int n0 = blockIdx.y * 64;
    const int tid  = threadIdx.x;
    const int wave = tid >> 6, lane = tid & 63;
    const int lrow = lane & 15, quad = lane >> 4;
    const int srow8 = lane >> 3;
    const int scol8 = ((lane & 7) ^ srow8) * 8;

    const ushort* gA = Ob + (size_t)(m0 + wave * 8 + srow8) * 1024 + scol8;
    const ushort* gB = Wb + (size_t)(n0 + wave * 8 + srow8) * 1024 + scol8;

    const int mw = wave * 32;            // 32 rows per wave, full 64-col width
    const int rsw = (lrow & 7);

    f32x4 acc[2][4];
#pragma unroll
    for (int i = 0; i < 2; i++)
#pragma unroll
        for (int j = 0; j < 4; j++) acc[i][j] = f32x4{0.f, 0.f, 0.f, 0.f};

    for (int k0 = 0; k0 < 1024; k0 += 64) {
        __syncthreads();
#pragma unroll
        for (int g = 0; g < 4; g++)
            gload16(gA + (size_t)g * 32 * 1024 + k0, &As[(g * 32 + wave * 8) * 64]);
#pragma unroll
        for (int g = 0; g < 2; g++)
            gload16(gB + (size_t)g * 32 * 1024 + k0, &Bs[(g * 32 + wave * 8) * 64]);
        __syncthreads();
#pragma unroll
        for (int ks = 0; ks < 2; ks++) {
            const int usw = ((ks * 4 + quad) ^ rsw) * 8;
            bf16x8 a[2], bfr[4];
#pragma unroll
            for (int i = 0; i < 2; i++)
                a[i] = *(const bf16x8*)&As[(mw + i * 16 + lrow) * 64 + usw];
#pragma unroll
            for (int j = 0; j < 4; j++)
                bfr[j] = *(const bf16x8*)&Bs[(j * 16 + lrow) * 64 + usw];
#pragma unroll
            for (int i = 0; i < 2; i++)
#pragma unroll
                for (int j = 0; j < 4; j++)
                    acc[i][j] = __builtin_amdgcn_mfma_f32_16x16x32_bf16(bfr[j], a[i], acc[i][j], 0, 0, 0);
        }
    }

    // C^T: lane holds m = mw+i*16+lrow, n = n0+j*16+quad*4+r -> float4 store
#pragma unroll
    for (int j = 0; j < 4; j++) {
        int n = n0 + j * 16 + quad * 4;
        float4 bv = *(const float4*)&bias[n];
#pragma unroll
        for (int i = 0; i < 2; i++) {
            int m = m0 + mw + i * 16 + lrow;
            float4 o;
            o.x = acc[i][j][0] + bv.x;
            o.y = acc[i][j][1] + bv.y;
            o.z = acc[i][j][2] + bv.z;
            o.w = acc[i][j][3] + bv.w;
            *(float4*)&out[(size_t)m * 1024 + n] = o;
        }
    }
}

extern "C" void kernel_launch(void* const* d_in, const int* in_sizes, int n_in,
                              void* d_out, int out_size, void* d_ws, size_t ws_size,
                              hipStream_t stream) {
    const float* x      = (const float*)d_in[0];
    const float* w_qkv  = (const float*)d_in[1];
    const float* b_qkv  = (const float*)d_in[2];
    const float* w_proj = (const float*)d_in[3];
    const float* b_proj = (const float*)d_in[4];
    float* out = (float*)d_out;

    char* ws = (char*)d_ws;
    ushort* Xb     = (ushort*)ws; ws += (size_t)B_ * T_ * E_ * 2;
    ushort* Wqkvb  = (ushort*)ws; ws += (size_t)3 * E_ * E_ * 2;
    ushort* Wprojb = (ushort*)ws; ws += (size_t)E_ * E_ * 2;
    ushort* Qb     = (ushort*)ws; ws += (size_t)B_ * H_ * T_ * DH_ * 2;
    ushort* Kb     = (ushort*)ws; ws += (size_t)B_ * H_ * T_ * DH_ * 2;
    ushort* Vtb    = (ushort*)ws; ws += (size_t)B_ * H_ * T_ * DH_ * 2;
    ushort* Ob     = (ushort*)ws; ws += (size_t)B_ * T_ * E_ * 2;

    int ntot = (B_ * T_ * E_ + 3 * E_ * E_ + E_ * E_) / 4;
    cvt_all<<<ntot / 256, 256, 0, stream>>>(x, w_qkv, w_proj, Xb, Wqkvb, Wprojb);

    gemm_qkv<<<dim3(64, 24), 256, 0, stream>>>(Xb, Wqkvb, b_qkv, Qb, Kb, Vtb);
    flash_attn<<<dim3(8, 64), 256, 0, stream>>>(Qb, Kb, Vtb, Ob);
    gemm_proj<<<dim3(64, 16), 256, 0, stream>>>(Ob, Wprojb, b_proj, out);
}